// Round 8
// baseline (117.265 us; speedup 1.0000x reference)
//
#include <hip/hip_runtime.h>
#include <math.h>

#define GN 8192
#define GF 64
#define GFIN 256
#define NEG 0.2f
#define NFINE 256
#define FCH 32      // ranks per fine chunk

// workspace layout (floats)
#define OFF_WH   0
#define OFF_S1   (GN*GF)
#define OFF_S2   (OFF_S1 + GN)
#define OFF_ZS   (OFF_S2 + GN)
#define OFF_IDX  (OFF_ZS + GN)              // int32: rank -> original row
#define OFF_RIDX (OFF_IDX + GN)             // int32: s1-desc-rank -> row
#define OFF_FA   (OFF_RIDX + GN)            // NFINE*GF fine sums, A side
#define OFF_FB   (OFF_FA + NFINE*GF)        // NFINE*GF fine sums, B side
#define OFF_FSA  (OFF_FB + NFINE*GF)        // NFINE scalar sums, A
#define OFF_FSB  (OFF_FSA + NFINE)          // NFINE scalar sums, B
#define ZERO_CNT (2*NFINE*GF + 2*NFINE)

// Kernel 1: Wh = h @ W, s1 = Wh@a1, s2 = Wh@a2; zero the atomic fine tables.
__global__ __launch_bounds__(256) void k_wh(const float* __restrict__ h,
        const float* __restrict__ W, const float* __restrict__ a,
        float* __restrict__ wsf) {
    float* Wh = wsf + OFF_WH;
    float* s1 = wsf + OFF_S1;
    float* s2 = wsf + OFF_S2;
    int t = threadIdx.x, b = blockIdx.x;
    int zm = b*256 + t;                      // 65536 threads cover 33280 slots
    if (zm < ZERO_CNT) wsf[OFF_FA + zm] = 0.f;
    __shared__ float Wl[GFIN*GF];            // 64 KB
    int lane = t & 63;
    const float4* W4 = (const float4*)W;
    float4* Wl4 = (float4*)Wl;
    #pragma unroll
    for (int m = 0; m < 16; ++m) Wl4[t + m*256] = W4[t + m*256];
    __syncthreads();
    int wid = __builtin_amdgcn_readfirstlane(t >> 6);   // SGPR wave id
    int row0 = b*32 + wid*8;
    const float* hrow = h + (size_t)row0 * GFIN;        // wave-uniform base
    float acc[8] = {0.f,0.f,0.f,0.f,0.f,0.f,0.f,0.f};
    #pragma unroll 8
    for (int k = 0; k < GFIN; ++k) {
        float wv = Wl[k*GF + lane];
        #pragma unroll
        for (int q = 0; q < 8; ++q) acc[q] += hrow[q*GFIN + k] * wv;
    }
    float a1 = a[lane], a2 = a[GF + lane];
    #pragma unroll
    for (int q = 0; q < 8; ++q) {
        int row = row0 + q;
        Wh[(size_t)row*GF + lane] = acc[q];
        float v1 = acc[q]*a1, v2 = acc[q]*a2;
        #pragma unroll
        for (int o = 32; o > 0; o >>= 1) { v1 += __shfl_xor(v1, o); v2 += __shfl_xor(v2, o); }
        if (lane == 0) { s1[row] = v1; s2[row] = v2; }
    }
}

// Kernel 2: DUAL rank in one sweep + atomic scatter.
//  - s2 strict-rank (index tiebreak) -> zs[rank], idx[rank]
//  - s1 DESCENDING strict-rank -> ridx[rank1] (rows ordered by split point)
//  - scatter exp-weighted Wh rows into fine chunk tables (rank>>5) by atomics
__global__ __launch_bounds__(512) void k_rank2(const float* __restrict__ Whg,
        float* __restrict__ wsf) {
    __shared__ float zl[GN];                 // s2 copy, 32 KB
    __shared__ float ol[GN];                 // s1 copy, 32 KB
    __shared__ int rl[32];
    __shared__ float redm[8];
    const float* s1 = wsf + OFF_S1;
    const float* s2 = wsf + OFF_S2;
    float* zs = wsf + OFF_ZS;
    int* idx = (int*)(wsf + OFF_IDX);
    int* ridx = (int*)(wsf + OFF_RIDX);
    float* fineA = wsf + OFF_FA;
    float* fineB = wsf + OFF_FB;
    float* fSA = wsf + OFF_FSA;
    float* fSB = wsf + OFF_FSB;
    int t = threadIdx.x, b = blockIdx.x;
    int lane = t & 63, wid = t >> 6;
    const float4* s4 = (const float4*)s2;
    const float4* o4g = (const float4*)s1;
    float4* z4 = (float4*)zl;
    float4* o4 = (float4*)ol;
    float mx = -1e30f;
    for (int m = t; m < GN/4; m += 512) {
        float4 v = s4[m]; z4[m] = v;
        o4[m] = o4g[m];
        mx = fmaxf(fmaxf(mx, v.x), fmaxf(fmaxf(v.y, v.z), v.w));
    }
    #pragma unroll
    for (int o = 32; o > 0; o >>= 1) mx = fmaxf(mx, __shfl_xor(mx, o));
    if (lane == 0) redm[wid] = mx;
    __syncthreads();
    float Z = redm[0];
    #pragma unroll
    for (int w2 = 1; w2 < 8; ++w2) Z = fmaxf(Z, redm[w2]);
    // dual rank: 32 j's per block, 16 slices each
    int jl = t >> 4, sl = t & 15;
    int j = b*32 + jl;
    float zj = zl[j];
    float oj = ol[j];
    int cnt = 0, cnt1 = 0;
    #pragma unroll 2
    for (int i = 0; i < 128; ++i) {
        int m4 = i*16 + sl;
        float4 v = z4[m4];
        float4 u = o4[m4];
        int mb = m4*4;
        cnt += (v.x < zj) || (v.x == zj && mb   < j);
        cnt += (v.y < zj) || (v.y == zj && mb+1 < j);
        cnt += (v.z < zj) || (v.z == zj && mb+2 < j);
        cnt += (v.w < zj) || (v.w == zj && mb+3 < j);
        cnt1 += (u.x > oj) || (u.x == oj && mb   < j);
        cnt1 += (u.y > oj) || (u.y == oj && mb+1 < j);
        cnt1 += (u.z > oj) || (u.z == oj && mb+2 < j);
        cnt1 += (u.w > oj) || (u.w == oj && mb+3 < j);
    }
    cnt  += __shfl_xor(cnt, 1);  cnt  += __shfl_xor(cnt, 2);
    cnt  += __shfl_xor(cnt, 4);  cnt  += __shfl_xor(cnt, 8);
    cnt1 += __shfl_xor(cnt1, 1); cnt1 += __shfl_xor(cnt1, 2);
    cnt1 += __shfl_xor(cnt1, 4); cnt1 += __shfl_xor(cnt1, 8);
    if (sl == 0) { zs[cnt] = zj; idx[cnt] = j; rl[jl] = cnt; ridx[cnt1] = j; }
    __syncthreads();
    // atomic scatter: 8 waves x 4 j's = the block's 32 rows (coalesced Wh)
    #pragma unroll
    for (int q = 0; q < 4; ++q) {
        int jj = wid*4 + q;
        int jg = b*32 + jj;
        int r = rl[jj];
        float d = zl[jg] - Z;
        float tA = __expf(d);
        float tB = __expf(NEG*d);
        float w = Whg[(size_t)jg*GF + lane];
        int fc = r >> 5;                     // FCH = 32
        atomicAdd(&fineA[fc*GF + lane], tA*w);
        atomicAdd(&fineB[fc*GF + lane], tB*w);
        if (lane == 0) atomicAdd(&fSA[fc], tA);
        if (lane == 1) atomicAdd(&fSB[fc], tB);
    }
}

// Kernel 3: outputs for 16 THRESHOLD-SORTED rows per block (via ridx).
// Shared base prefix/suffix at the block's [fcmin,fcmax], tiny per-row walk,
// exact 32-rank boundary fix. All fine-table reads coalesced.
__global__ __launch_bounds__(256) void k_out(const float* __restrict__ wsf,
        float* __restrict__ out) {
    __shared__ float zl[GN];                 // 32 KB sorted zs
    __shared__ int fcs[16];
    __shared__ float cb[4][66];              // B base partials (+scalar at 64)
    __shared__ float ca[4][66];              // A base partials
    const float* Wh = wsf + OFF_WH;
    const float* s1 = wsf + OFF_S1;
    const float* zs = wsf + OFF_ZS;
    const int* idx = (const int*)(wsf + OFF_IDX);
    const int* ridx = (const int*)(wsf + OFF_RIDX);
    const float* fineA = wsf + OFF_FA;
    const float* fineB = wsf + OFF_FB;
    const float* fSA = wsf + OFF_FSA;
    const float* fSB = wsf + OFF_FSB;
    int t = threadIdx.x, b = blockIdx.x;
    int lane = t & 63, wid = t >> 6;
    const float4* g4 = (const float4*)zs;
    float4* z4 = (float4*)zl;
    #pragma unroll
    for (int m = 0; m < 8; ++m) z4[t + m*256] = g4[t + m*256];
    __syncthreads();
    float Z = zl[GN-1];
    int ir_[4]; float s1v[4], aA[4], aB[4];
    #pragma unroll
    for (int q = 0; q < 4; ++q) {
        int rr = b*16 + wid*4 + q;
        ir_[q] = ridx[rr];                   // wave-uniform s_load
        float s1i = s1[ir_[q]];
        s1v[q] = s1i;
        float g = s1i + Z;
        float m = (g >= 0.f) ? g : NEG*g;    // LeakyReLU(g) = row max of e
        aA[q] = __expf(g - m);               // <= 1
        aB[q] = __expf(NEG*g - m);           // <= 1
    }
    int lo[4] = {0,0,0,0}, hi[4] = {GN,GN,GN,GN};
    #pragma unroll
    for (int it = 0; it < 13; ++it) {        // lower_bound on LDS zs
        #pragma unroll
        for (int q = 0; q < 4; ++q) {
            int mid = (lo[q]+hi[q]) >> 1;
            if (zl[mid] < -s1v[q]) lo[q] = mid+1; else hi[q] = mid;
        }
    }
    #pragma unroll
    for (int q = 0; q < 4; ++q)
        if (lane == 0) fcs[wid*4+q] = min(lo[q] >> 5, NFINE-1);
    __syncthreads();
    int fcmin = NFINE, fcmax = 0;
    #pragma unroll
    for (int e = 0; e < 16; ++e) { int f = fcs[e]; fcmin = min(fcmin, f); fcmax = max(fcmax, f); }
    // base partials: waves split the chunk streams 4-way (coalesced)
    float pB = 0.f, psB = 0.f, pA = 0.f, psA = 0.f;
    for (int ch = wid; ch < fcmin; ch += 4) { pB += fineB[ch*GF + lane]; psB += fSB[ch]; }
    for (int ch = fcmax+1+wid; ch < NFINE; ch += 4) { pA += fineA[ch*GF + lane]; psA += fSA[ch]; }
    cb[wid][lane] = pB; ca[wid][lane] = pA;
    if (lane == 0) { cb[wid][64] = psB; ca[wid][64] = psA; }
    __syncthreads();
    float baseB = 0.f, baseSB = 0.f, baseA = 0.f, baseSA = 0.f;
    #pragma unroll
    for (int w2 = 0; w2 < 4; ++w2) {
        baseB += cb[w2][lane]; baseSB += cb[w2][64];
        baseA += ca[w2][lane]; baseSA += ca[w2][64];
    }
    #pragma unroll
    for (int q = 0; q < 4; ++q) {
        int k = lo[q];
        int fq = min(k >> 5, NFINE-1);
        float vb = baseB, pb = baseSB;
        for (int ch = fcmin; ch < fq; ++ch) { vb += fineB[ch*GF + lane]; pb += fSB[ch]; }
        float va = baseA, sa = baseSA;
        for (int ch = fq+1; ch <= fcmax; ++ch) { va += fineA[ch*GF + lane]; sa += fSA[ch]; }
        #pragma unroll 8
        for (int e = 0; e < FCH; ++e) {
            int r = fq*FCH + e;
            float zr = zl[r];
            int ir = idx[r];
            float w = Wh[(size_t)ir*GF + lane];
            float d = zr - Z;
            if (r >= k) { float tA = __expf(d);     va += tA*w; sa += tA; }
            else        { float tB = __expf(NEG*d); vb += tB*w; pb += tB; }
        }
        out[(size_t)ir_[q]*GF + lane] = (aA[q]*va + aB[q]*vb) / (aA[q]*sa + aB[q]*pb);
    }
}

extern "C" void kernel_launch(void* const* d_in, const int* in_sizes, int n_in,
                              void* d_out, int out_size, void* d_ws, size_t ws_size,
                              hipStream_t stream) {
    const float* h = (const float*)d_in[0];
    // d_in[1] = adj (unused by the reference forward)
    const float* W = (const float*)d_in[2];
    const float* a = (const float*)d_in[3];
    float* wsf = (float*)d_ws;
    float* out = (float*)d_out;

    hipLaunchKernelGGL(k_wh,    dim3(GN/32), dim3(256), 0, stream, h, W, a, wsf);
    hipLaunchKernelGGL(k_rank2, dim3(GN/32), dim3(512), 0, stream, wsf + OFF_WH, wsf);
    hipLaunchKernelGGL(k_out,   dim3(GN/16), dim3(256), 0, stream, wsf, out);
}

// Round 9
// 70.989 us; speedup vs baseline: 1.6519x; 1.6519x over previous
//
#include <hip/hip_runtime.h>
#include <math.h>

#define GN 8192
#define GF 64
#define GFIN 256
#define NEG 0.2f
#define NFINE 256
#define FCH 32      // ranks per fine chunk

// workspace layout (floats)
#define OFF_WH   0
#define OFF_S1   (GN*GF)
#define OFF_S2   (OFF_S1 + GN)
#define OFF_ZS   (OFF_S2 + GN)
#define OFF_IDX  (OFF_ZS + GN)              // int32: rank -> original row
#define OFF_FA   (OFF_IDX + GN)             // NFINE*GF fine sums, A (atomic)
#define OFF_FB   (OFF_FA + NFINE*GF)        // NFINE*GF fine sums, B (atomic)
#define OFF_FSA  (OFF_FB + NFINE*GF)        // NFINE scalar sums, A
#define OFF_FSB  (OFF_FSA + NFINE)          // NFINE scalar sums, B
#define OFF_OFA  (OFF_FSB + NFINE)          // NFINE*GF exclusive suffix, A
#define OFF_OFB  (OFF_OFA + NFINE*GF)       // NFINE*GF exclusive prefix, B
#define OFF_OSA  (OFF_OFB + NFINE*GF)       // NFINE scalar, A
#define OFF_OSB  (OFF_OSA + NFINE)          // NFINE scalar, B
#define ZERO_CNT (2*NFINE*GF + 2*NFINE)     // FA..FSB contiguous

// Kernel 1: Wh = h @ W, s1 = Wh@a1, s2 = Wh@a2; zero the atomic fine tables.
// W staged TRANSPOSED in LDS with XOR swizzle: element (c,k) at
// c*256 + (k ^ ((c&7)<<2)) -> ds_read_b128 hits all 32 banks evenly (8cy floor)
// instead of 256 scalar b32 reads per thread.
__global__ __launch_bounds__(512) void k_wh(const float* __restrict__ h,
        const float* __restrict__ W, const float* __restrict__ a,
        float* __restrict__ wsf) {
    float* Wh = wsf + OFF_WH;
    float* s1 = wsf + OFF_S1;
    float* s2 = wsf + OFF_S2;
    __shared__ float WlT[GF*GFIN];           // 64 KB
    int t = threadIdx.x, b = blockIdx.x;
    int zm = b*512 + t;                      // 131072 threads cover 33280 slots
    if (zm < ZERO_CNT) wsf[OFF_FA + zm] = 0.f;
    int lane = t & 63;
    // stage W (swizzled transpose): 4096 float4, 8 per thread
    const float4* W4 = (const float4*)W;
    #pragma unroll
    for (int m = 0; m < 8; ++m) {
        int g = t + m*512;
        float4 v = W4[g];
        int k = g >> 4;                      // W row (k-dim)
        int c0 = (g & 15) * 4;               // 4 consecutive output channels
        WlT[(c0  )*GFIN + (k ^ (((c0  )&7)<<2))] = v.x;
        WlT[(c0+1)*GFIN + (k ^ (((c0+1)&7)<<2))] = v.y;
        WlT[(c0+2)*GFIN + (k ^ (((c0+2)&7)<<2))] = v.z;
        WlT[(c0+3)*GFIN + (k ^ (((c0+3)&7)<<2))] = v.w;
    }
    __syncthreads();
    int wid = __builtin_amdgcn_readfirstlane(t >> 6);   // SGPR wave id
    int row0 = b*32 + wid*4;
    const float* hrow = h + (size_t)row0 * GFIN;        // wave-uniform base
    float acc[4] = {0.f,0.f,0.f,0.f};
    const float4* WlT4 = (const float4*)WlT;
    int cbase = lane * (GFIN/4);
    int sw = lane & 7;
    #pragma unroll 8
    for (int k4 = 0; k4 < GFIN/4; ++k4) {
        float4 wv = WlT4[cbase + (k4 ^ sw)];
        int kk = k4*4;
        #pragma unroll
        for (int q = 0; q < 4; ++q) {
            acc[q] += hrow[q*GFIN + kk  ] * wv.x;
            acc[q] += hrow[q*GFIN + kk+1] * wv.y;
            acc[q] += hrow[q*GFIN + kk+2] * wv.z;
            acc[q] += hrow[q*GFIN + kk+3] * wv.w;
        }
    }
    float a1 = a[lane], a2 = a[GF + lane];
    #pragma unroll
    for (int q = 0; q < 4; ++q) {
        int row = row0 + q;
        Wh[(size_t)row*GF + lane] = acc[q];
        float v1 = acc[q]*a1, v2 = acc[q]*a2;
        #pragma unroll
        for (int o = 32; o > 0; o >>= 1) { v1 += __shfl_xor(v1, o); v2 += __shfl_xor(v2, o); }
        if (lane == 0) { s1[row] = v1; s2[row] = v2; }
    }
}

// Kernel 2: rank-sort s2 (strict total order, index tiebreak) + atomic scatter
// of exp-weighted Wh rows into fine-chunk tables (rank>>5). Scatter is
// coalesced (row-major Wh reads) and was measured ~free (R5 vs R6).
__global__ __launch_bounds__(512) void k_rank(const float* __restrict__ Whg,
        float* __restrict__ wsf) {
    __shared__ float zl[GN];                 // 32 KB s2 copy
    __shared__ int rl[32];
    __shared__ float redm[8];
    const float* s2 = wsf + OFF_S2;
    float* zs = wsf + OFF_ZS;
    int* idx = (int*)(wsf + OFF_IDX);
    float* fineA = wsf + OFF_FA;
    float* fineB = wsf + OFF_FB;
    float* fSA = wsf + OFF_FSA;
    float* fSB = wsf + OFF_FSB;
    int t = threadIdx.x, b = blockIdx.x;
    int lane = t & 63, wid = t >> 6;
    const float4* s4 = (const float4*)s2;
    float4* z4 = (float4*)zl;
    float mx = -1e30f;
    for (int m = t; m < GN/4; m += 512) {
        float4 v = s4[m]; z4[m] = v;
        mx = fmaxf(fmaxf(mx, v.x), fmaxf(fmaxf(v.y, v.z), v.w));
    }
    #pragma unroll
    for (int o = 32; o > 0; o >>= 1) mx = fmaxf(mx, __shfl_xor(mx, o));
    if (lane == 0) redm[wid] = mx;
    __syncthreads();
    float Z = redm[0];
    #pragma unroll
    for (int w2 = 1; w2 < 8; ++w2) Z = fmaxf(Z, redm[w2]);
    // rank: 32 j's per block, 16 slices each
    int jl = t >> 4, sl = t & 15;
    int j = b*32 + jl;
    float zj = zl[j];
    int cnt = 0;
    #pragma unroll 4
    for (int i = 0; i < GN/64; ++i) {        // 128 iters x float4
        int m4 = i*16 + sl;
        float4 v = z4[m4];
        int mb = m4*4;
        cnt += (v.x < zj) || (v.x == zj && mb   < j);
        cnt += (v.y < zj) || (v.y == zj && mb+1 < j);
        cnt += (v.z < zj) || (v.z == zj && mb+2 < j);
        cnt += (v.w < zj) || (v.w == zj && mb+3 < j);
    }
    cnt += __shfl_xor(cnt, 1);
    cnt += __shfl_xor(cnt, 2);
    cnt += __shfl_xor(cnt, 4);
    cnt += __shfl_xor(cnt, 8);
    if (sl == 0) { zs[cnt] = zj; idx[cnt] = j; rl[jl] = cnt; }
    __syncthreads();
    // atomic scatter: 8 waves x 4 j's = the block's 32 rows (coalesced Wh)
    #pragma unroll
    for (int q = 0; q < 4; ++q) {
        int jj = wid*4 + q;
        int jg = b*32 + jj;
        int r = rl[jj];
        float d = zl[jg] - Z;
        float tA = __expf(d);
        float tB = __expf(NEG*d);
        float w = Whg[(size_t)jg*GF + lane];
        int fc = r >> 5;                     // FCH = 32
        atomicAdd(&fineA[fc*GF + lane], tA*w);
        atomicAdd(&fineB[fc*GF + lane], tB*w);
        if (lane == 0) atomicAdd(&fSA[fc], tA);
        if (lane == 1) atomicAdd(&fSB[fc], tB);
    }
}

// Kernel 3: tiny pure scan over the 256 fine-chunk totals (no gathers).
// Block c (0..63) = channel c; block 64 = scalar channels. Thread t = chunk t.
// B: exclusive prefix; A: TRUE reversed exclusive suffix.
__global__ __launch_bounds__(256) void k_scan(float* __restrict__ wsf) {
    __shared__ float stg[NFINE];
    __shared__ float wred[4];
    const float* fineA = wsf + OFF_FA;
    const float* fineB = wsf + OFF_FB;
    const float* fSA = wsf + OFF_FSA;
    const float* fSB = wsf + OFF_FSB;
    float* ofA = wsf + OFF_OFA;
    float* ofB = wsf + OFF_OFB;
    float* osA = wsf + OFF_OSA;
    float* osB = wsf + OFF_OSB;
    int c = blockIdx.x;
    int t = threadIdx.x, lane = t & 63, wid = t >> 6;
    float fA = (c < 64) ? fineA[t*GF + c] : fSA[t];
    float fB = (c < 64) ? fineB[t*GF + c] : fSB[t];
    // ---- B: exclusive prefix over chunk index t ----
    {
        float ws = fB;
        #pragma unroll
        for (int o = 1; o < 64; o <<= 1) { float y = __shfl_up(ws, o); if (lane >= o) ws += y; }
        if (lane == 63) wred[wid] = ws;
        __syncthreads();
        float blkoff = 0.f;
        #pragma unroll
        for (int w2 = 0; w2 < 4; ++w2) { float x = wred[w2]; if (w2 < wid) blkoff += x; }
        float exB = blkoff + ws - fB;
        if (c < 64) ofB[t*GF + c] = exB; else osB[t] = exB;
    }
    __syncthreads();
    // ---- A: exclusive suffix = reversed exclusive prefix (true scan) ----
    stg[t] = fA;
    __syncthreads();
    {
        int rt = NFINE-1-t;
        float vA = stg[rt];
        float ws = vA;
        #pragma unroll
        for (int o = 1; o < 64; o <<= 1) { float y = __shfl_up(ws, o); if (lane >= o) ws += y; }
        __syncthreads();                     // wred reuse
        if (lane == 63) wred[wid] = ws;
        __syncthreads();
        float blkoff = 0.f;
        #pragma unroll
        for (int w2 = 0; w2 < 4; ++w2) { float x = wred[w2]; if (w2 < wid) blkoff += x; }
        float exA = blkoff + ws - vA;        // sum over chunks > rt
        if (c < 64) ofA[rt*GF + c] = exA; else osA[rt] = exA;
    }
}

// Kernel 4: per-row output (R7 verbatim). One wave per row, 2048 blocks
// (8 blocks/CU, 32 waves/CU). Global binary search + point table reads +
// exact 32-rank boundary fix.
__global__ __launch_bounds__(256) void k_out(const float* __restrict__ wsf,
        float* __restrict__ out) {
    const float* Wh = wsf + OFF_WH;
    const float* s1 = wsf + OFF_S1;
    const float* zs = wsf + OFF_ZS;
    const int* idx = (const int*)(wsf + OFF_IDX);
    const float* ofA = wsf + OFF_OFA;
    const float* ofB = wsf + OFF_OFB;
    const float* osA = wsf + OFF_OSA;
    const float* osB = wsf + OFF_OSB;
    int t = threadIdx.x;
    int wid = t >> 6, lane = t & 63;
    int i = blockIdx.x*4 + wid;
    float s1i = s1[i];
    float Z = zs[GN-1];
    float g = s1i + Z;
    float m = (g >= 0.f) ? g : NEG*g;        // LeakyReLU(g) = row max of e
    float aA = __expf(g - m);                // <= 1
    float aB = __expf(NEG*g - m);            // <= 1
    float tgt = -s1i;
    int lo = 0, hi = GN;                     // lower_bound: first zs[k] >= tgt
    #pragma unroll
    for (int it = 0; it < 13; ++it) {
        int mid = (lo + hi) >> 1;
        if (zs[mid] < tgt) lo = mid + 1; else hi = mid;
    }
    int k = lo;
    int fc = __builtin_amdgcn_readfirstlane(min(k >> 5, NFINE-1));
    float va = ofA[fc*GF + lane];            // sum over chunks > fc (A side)
    float vb = ofB[fc*GF + lane];            // sum over chunks < fc (B side)
    float sa = osA[fc], pb = osB[fc];
    #pragma unroll 8
    for (int q = 0; q < FCH; ++q) {
        int r = fc*FCH + q;
        float zr = zs[r];
        int ir = idx[r];
        float w = Wh[(size_t)ir*GF + lane];
        float d = zr - Z;
        if (r >= k) { float tA = __expf(d);     va += tA*w; sa += tA; }
        else        { float tB = __expf(NEG*d); vb += tB*w; pb += tB; }
    }
    out[(size_t)i*GF + lane] = (aA*va + aB*vb) / (aA*sa + aB*pb);
}

extern "C" void kernel_launch(void* const* d_in, const int* in_sizes, int n_in,
                              void* d_out, int out_size, void* d_ws, size_t ws_size,
                              hipStream_t stream) {
    const float* h = (const float*)d_in[0];
    // d_in[1] = adj (unused by the reference forward)
    const float* W = (const float*)d_in[2];
    const float* a = (const float*)d_in[3];
    float* wsf = (float*)d_ws;
    float* out = (float*)d_out;

    hipLaunchKernelGGL(k_wh,   dim3(GN/32), dim3(512), 0, stream, h, W, a, wsf);
    hipLaunchKernelGGL(k_rank, dim3(GN/32), dim3(512), 0, stream, wsf + OFF_WH, wsf);
    hipLaunchKernelGGL(k_scan, dim3(65),    dim3(256), 0, stream, wsf);
    hipLaunchKernelGGL(k_out,  dim3(GN/4),  dim3(256), 0, stream, wsf, out);
}